// Round 14
// baseline (26406.772 us; speedup 1.0000x reference)
//
#include <hip/hip_runtime.h>
#include <stdint.h>

// DecoderRNN R14: R12 base (proven 17.9ms) + fused y-hop + register-carried h-old.
// - y partials: role3 does ONE 64-bit atomic fetch_add per batch into an 8-deep
//   ring: high32 = arrival count, low32 = biased fixed-point sum (scale 2^14,
//   bias 512 -> addend<2^24, 32 adds<2^29, no carry into count). Data IS the
//   flag: role0 polls count==32 then decodes. Deletes role3's drain+flag and
//   role0's y-wait + 32-word read. WG0 zero-aheads slot (t+4)&7 (transitively
//   ordered via h0-flag -> role2 -> role3 chain).
// - roles 0/2 carry their own h-old in registers (computed it last step).
// Everything else identical to R12: mailbox p2p, swap stores -> LLC, sc0/sc1
// coherent loads, no fences in loop, whole-WG drain_sync/waitmail.

#define NWG 128
#define NT  256
#define TT  1024

typedef unsigned short ushort;
typedef unsigned int   uint;
typedef unsigned long long ull;
typedef __attribute__((ext_vector_type(8))) short short8;
typedef __attribute__((ext_vector_type(4))) float f32x4;
typedef __attribute__((ext_vector_type(4))) uint  uint4v;

struct __align__(16) Smem {
  ushort wpl[2][48*520];
  float  gictx[3*16*68];
  float  wcol[3][16];
  float  bsumR[16], bsumZ[16], binN[16], bhnN[16];
  float  bo1v[16], wo2v[16];
};

__device__ __forceinline__ float sigm(float x){ return 1.f/(1.f + expf(-x)); }
__device__ __forceinline__ float bf2f(ushort h){ return __uint_as_float(((uint)h)<<16); }
__device__ __forceinline__ ushort bfrnd(float x){
  uint u = __float_as_uint(x);
  return (ushort)((u + 0x7fffu + ((u>>16)&1u)) >> 16);
}
__device__ __forceinline__ float unpk(uint p){
  return bf2f((ushort)(p >> 16)) + bf2f((ushort)(p & 0xffffu));
}
__device__ __forceinline__ uint pkh(float h){
  ushort hb = bfrnd(h);
  ushort lb = bfrnd(h - bf2f(hb));
  return ((uint)hb << 16) | (uint)lb;
}
__device__ __forceinline__ short8 hi8(uint4v a, uint4v b){
  uint d0 = __builtin_amdgcn_perm(a.y, a.x, 0x07060302u);
  uint d1 = __builtin_amdgcn_perm(a.w, a.z, 0x07060302u);
  uint d2 = __builtin_amdgcn_perm(b.y, b.x, 0x07060302u);
  uint d3 = __builtin_amdgcn_perm(b.w, b.z, 0x07060302u);
  return __builtin_bit_cast(short8, (uint4v){d0,d1,d2,d3});
}
__device__ __forceinline__ short8 lo8(uint4v a, uint4v b){
  uint d0 = __builtin_amdgcn_perm(a.y, a.x, 0x05040100u);
  uint d1 = __builtin_amdgcn_perm(a.w, a.z, 0x05040100u);
  uint d2 = __builtin_amdgcn_perm(b.y, b.x, 0x05040100u);
  uint d3 = __builtin_amdgcn_perm(b.w, b.z, 0x05040100u);
  return __builtin_bit_cast(short8, (uint4v){d0,d1,d2,d3});
}
#define SWP(p, v)   (void)__hip_atomic_exchange((uint*)(p), (uint)(v), __ATOMIC_RELAXED, __HIP_MEMORY_SCOPE_AGENT)
#define SWPF(p, v)  SWP((p), __float_as_uint(v))
#define SWP64(p, v) (void)__hip_atomic_exchange((ull*)(p), (ull)(v), __ATOMIC_RELAXED, __HIP_MEMORY_SCOPE_AGENT)
#define ALD1(p)     __hip_atomic_load((const uint*)(p), __ATOMIC_RELAXED, __HIP_MEMORY_SCOPE_AGENT)
#define ALD8(p)     __hip_atomic_load((const ull*)(p), __ATOMIC_RELAXED, __HIP_MEMORY_SCOPE_AGENT)
#define ALDF(p)     __uint_as_float(ALD1(p))
#define FADDI(p)    (void)__hip_atomic_fetch_add((p), 1, __ATOMIC_RELAXED, __HIP_MEMORY_SCOPE_AGENT)
#define FADD64(p,x) (void)__hip_atomic_fetch_add((ull*)(p), (ull)(x), __ATOMIC_RELAXED, __HIP_MEMORY_SCOPE_AGENT)
#define YSCALE 16384.0f
#define YBIAS  512.0f

// init-only global barrier (poison-safe epochs)
__device__ __forceinline__ void gbar(int* slots, int* epoch, int w, int tid, int e){
  __syncthreads();
  if (tid == 0)
    __hip_atomic_store(&slots[w], e, __ATOMIC_RELEASE, __HIP_MEMORY_SCOPE_AGENT);
  if (w == 0 && tid < 64){
    for(;;){
      int m0 = __hip_atomic_load(&slots[tid*2+0], __ATOMIC_RELAXED, __HIP_MEMORY_SCOPE_AGENT);
      int m1 = __hip_atomic_load(&slots[tid*2+1], __ATOMIC_RELAXED, __HIP_MEMORY_SCOPE_AGENT);
      if (__all(min(m0,m1) >= e)) break;
      __builtin_amdgcn_s_sleep(1);
    }
    if (tid == 0){
      __builtin_amdgcn_fence(__ATOMIC_ACQUIRE, "agent");
      __hip_atomic_store(epoch, e, __ATOMIC_RELEASE, __HIP_MEMORY_SCOPE_AGENT);
    }
  }
  if (tid == 0){
    while (__hip_atomic_load(epoch, __ATOMIC_RELAXED, __HIP_MEMORY_SCOPE_AGENT) < e)
      __builtin_amdgcn_s_sleep(1);
    __builtin_amdgcn_fence(__ATOMIC_ACQUIRE, "agent");
  }
  __syncthreads();
}

__device__ __forceinline__ void drain_sync(){
  __builtin_amdgcn_s_waitcnt(0);
  __syncthreads();
}
// consumer poll: 1 lane, 1 dword, NO fence (loop loads are all LLC-coherent)
__device__ __forceinline__ void waitmail(const int* w, int target, int tid){
  if (tid == 0)
    while ((int)ALD1(w) < target) __builtin_amdgcn_s_sleep(1);
  __syncthreads();
}
__device__ __forceinline__ void finfence(int tid){
  if (tid == 0) __builtin_amdgcn_fence(__ATOMIC_ACQUIRE, "agent");
  __syncthreads();
}

// coherent LLC-direct 16B load (sc0 sc1 = bypass L1+L2)
#define LDSC(P, i) \
  asm volatile("global_load_dwordx4 %0, %1, off sc0 sc1" \
               : "=v"(pa##i) : "v"((P) + aoff + (i)*32)); \
  asm volatile("global_load_dwordx4 %0, %1, off sc0 sc1" \
               : "=v"(pb##i) : "v"((P) + aoff + (i)*32 + 4));
#define VMBAR8(a,b,c,d,e,f,g,h) \
  asm volatile("s_waitcnt vmcnt(0)" \
               : "+v"(a),"+v"(b),"+v"(c),"+v"(d),"+v"(e),"+v"(f),"+v"(g),"+v"(h));
#define DECL_LOADS(P) \
  uint4v pa0,pa1,pa2,pa3,pa4,pa5,pa6,pa7,pa8,pa9,pa10,pa11,pa12,pa13,pa14,pa15; \
  uint4v pb0,pb1,pb2,pb3,pb4,pb5,pb6,pb7,pb8,pb9,pb10,pb11,pb12,pb13,pb14,pb15; \
  LDSC(P,0) LDSC(P,1) LDSC(P,2) LDSC(P,3) LDSC(P,4) LDSC(P,5) LDSC(P,6) LDSC(P,7) \
  LDSC(P,8) LDSC(P,9) LDSC(P,10) LDSC(P,11) LDSC(P,12) LDSC(P,13) LDSC(P,14) LDSC(P,15) \
  VMBAR8(pa0,pb0,pa1,pb1,pa2,pb2,pa3,pb3) \
  VMBAR8(pa4,pb4,pa5,pb5,pa6,pb6,pa7,pb7) \
  VMBAR8(pa8,pb8,pa9,pb9,pa10,pb10,pa11,pb11) \
  VMBAR8(pa12,pb12,pa13,pb13,pa14,pb14,pa15,pb15)

#define MS3(i) { \
  short8 AH_ = hi8(pa##i, pb##i); \
  short8 AL_ = lo8(pa##i, pb##i); \
  const int ko_ = (i)*32 + q*8; \
  short8 bh_ = *(const short8*)(&S.wpl[0][(col)*520 + ko_]); \
  short8 bl_ = *(const short8*)(&S.wpl[1][(col)*520 + ko_]); \
  acc0 = __builtin_amdgcn_mfma_f32_16x16x32_bf16(AH_, bh_, acc0, 0,0,0); \
  acc0 = __builtin_amdgcn_mfma_f32_16x16x32_bf16(AL_, bh_, acc0, 0,0,0); \
  acc0 = __builtin_amdgcn_mfma_f32_16x16x32_bf16(AH_, bl_, acc0, 0,0,0); \
  bh_ = *(const short8*)(&S.wpl[0][(16+col)*520 + ko_]); \
  bl_ = *(const short8*)(&S.wpl[1][(16+col)*520 + ko_]); \
  acc1 = __builtin_amdgcn_mfma_f32_16x16x32_bf16(AH_, bh_, acc1, 0,0,0); \
  acc1 = __builtin_amdgcn_mfma_f32_16x16x32_bf16(AL_, bh_, acc1, 0,0,0); \
  acc1 = __builtin_amdgcn_mfma_f32_16x16x32_bf16(AH_, bl_, acc1, 0,0,0); \
  bh_ = *(const short8*)(&S.wpl[0][(32+col)*520 + ko_]); \
  bl_ = *(const short8*)(&S.wpl[1][(32+col)*520 + ko_]); \
  acc2 = __builtin_amdgcn_mfma_f32_16x16x32_bf16(AH_, bh_, acc2, 0,0,0); \
  acc2 = __builtin_amdgcn_mfma_f32_16x16x32_bf16(AL_, bh_, acc2, 0,0,0); \
  acc2 = __builtin_amdgcn_mfma_f32_16x16x32_bf16(AH_, bl_, acc2, 0,0,0); }

#define MS1(i) { \
  short8 AH_ = hi8(pa##i, pb##i); \
  short8 AL_ = lo8(pa##i, pb##i); \
  const int ko_ = (i)*32 + q*8; \
  short8 bh_ = *(const short8*)(&S.wpl[0][(col)*520 + ko_]); \
  short8 bl_ = *(const short8*)(&S.wpl[1][(col)*520 + ko_]); \
  acc0 = __builtin_amdgcn_mfma_f32_16x16x32_bf16(AH_, bh_, acc0, 0,0,0); \
  acc0 = __builtin_amdgcn_mfma_f32_16x16x32_bf16(AL_, bh_, acc0, 0,0,0); \
  acc0 = __builtin_amdgcn_mfma_f32_16x16x32_bf16(AH_, bl_, acc0, 0,0,0); }

#define RUN16(M) M(0) M(1) M(2) M(3) M(4) M(5) M(6) M(7) \
                 M(8) M(9) M(10) M(11) M(12) M(13) M(14) M(15)

extern "C" __global__ void __launch_bounds__(NT, 1)
decoder_rnn(const float* __restrict__ ctx,   // [64][512]
            const float* __restrict__ Wih0,  // [1536][513] (row stride 513!)
            const float* __restrict__ Whh0,
            const float* __restrict__ bih0,
            const float* __restrict__ bhh0g,
            const float* __restrict__ Wih1,
            const float* __restrict__ Whh1,
            const float* __restrict__ bih1g,
            const float* __restrict__ bhh1g,
            const float* __restrict__ Wo1,
            const float* __restrict__ bo1g,
            const float* __restrict__ Wo2,
            const float* __restrict__ bo2g,
            float* __restrict__ out,         // [64*1024 y][65536 h_i]
            float* __restrict__ ws)
{
  extern __shared__ char smem_raw[];
  Smem& S = *reinterpret_cast<Smem*>(smem_raw);
  const int tid = threadIdx.x;
  const int wg  = blockIdx.x;

  uint*  hpk    = (uint*)ws;                 // h0pk 2x32768 | h1pk 32768
  float* gh1raw = (float*)ws + 98304;        // 32*3072
  ull*   yring  = (ull*)((float*)ws + 196608); // 8 slots x 64 batches x u64
  int*   ibase  = (int*)((float*)ws + 200704);
  int*   gslots = ibase;                     // [128] init gbar
  int*   epoch  = ibase + 128;
  int*   mbox   = ibase + 256;               // 128 lines x 32 ints (128B/line)

  const float bo2v = bo2g[0];

  // ---------------- init (swaps -> LLC) ----------------
  for (int i = wg*NT + tid; i < 32768; i += NWG*NT){
    SWP(hpk + i, 0u);
    SWP(hpk + 65536 + i, 0u);
  }
  if (wg == 0){
    for (int i = tid; i < NWG*32; i += NT) SWP(mbox + i, 0);
    for (int i = tid; i < 512; i += NT) SWP64(yring + i, 0ULL);
  }

  const int role = wg >> 5;
  const int j    = wg & 31;
  if (role != 3){
    const float* Wsrc = (role == 0) ? Whh0 : (role == 1) ? Whh1 : Wih1;
    for (int i = tid; i < 48*512; i += NT){
      int r = i >> 9, k = i & 511;
      int g = r >> 4, n = r & 15;
      float wv = Wsrc[(size_t)(g*512 + 16*j + n)*512 + k];
      ushort hh = bfrnd(wv);
      S.wpl[0][r*520 + k] = hh;
      S.wpl[1][r*520 + k] = bfrnd(wv - bf2f(hh));
    }
  } else {
    for (int i = tid; i < 16*512; i += NT){
      int r = i >> 9, k = i & 511;
      float wv = Wo1[(size_t)(16*j + r)*512 + k];
      ushort hh = bfrnd(wv);
      S.wpl[0][r*520 + k] = hh;
      S.wpl[1][r*520 + k] = bfrnd(wv - bf2f(hh));
    }
    if (tid < 16){ S.bo1v[tid] = bo1g[16*j + tid]; S.wo2v[tid] = Wo2[16*j + tid]; }
  }
  if (role == 0){
    if (tid < 48){
      int g = tid >> 4, n = tid & 15;
      S.wcol[g][n] = Wih0[(size_t)(g*512 + 16*j + n)*513 + 512];
    }
    if (tid < 16) S.bhnN[tid] = bhh0g[2*512 + 16*j + tid];
    for (int idx = tid; idx < 3072; idx += NT){
      int r = idx >> 6, b = idx & 63;
      int g = r >> 4, n = r & 15;
      int grow = g*512 + 16*j + n;
      const float* wr = Wih0 + (size_t)grow*513;
      const float* cx = ctx  + (size_t)b*512;
      float s = bih0[grow];
      if (g < 2) s += bhh0g[grow];
      #pragma unroll 4
      for (int k = 0; k < 512; ++k) s += wr[k]*cx[k];
      S.gictx[g*1088 + n*68 + b] = s;
    }
  }
  if (role == 2 && tid < 16){
    int n = tid;
    S.bsumR[n] = bih1g[16*j + n]       + bhh1g[16*j + n];
    S.bsumZ[n] = bih1g[512 + 16*j + n] + bhh1g[512 + 16*j + n];
    S.binN[n]  = bih1g[1024 + 16*j + n];
    S.bhnN[n]  = bhh1g[1024 + 16*j + n];
  }

  gbar(gslots, epoch, wg, tid, 1);

  int* myline = mbox + wg*32;

  const int v   = tid >> 6;
  const int l   = tid & 63;
  const int q   = l >> 4;
  const int col = l & 15;
  const int aoff = (16*v + col)*512 + q*8;
  const int b0w  = 16*v + 4*q;
  const int ng   = 16*j + col;

  if (role == 0){
    float hc0 = 0.f, hc1 = 0.f, hc2 = 0.f, hc3 = 0.f;   // carried h0-old
    for (int t = 0; t < TT; ++t){
      const int r0 = t & 1, w0 = r0 ^ 1;
      waitmail(myline + 0, 32*t, tid);       // h0[t-1] peers at LLC
      const uint* rP = hpk + r0*32768;
      uint*       wP = hpk + w0*32768;
      f32x4 acc0={0,0,0,0}, acc1={0,0,0,0}, acc2={0,0,0,0};
      DECL_LOADS(rP)
      RUN16(MS3)
      // ---- y[t-1]: fused count+value ring; col==0 lanes poll+decode ----
      f32x4 pv4 = {0,0,0,0};
      if (t > 0){
        f32x4 dv = {0,0,0,0};
        if (col == 0){
          const ull* yp = yring + ((size_t)((t-1) & 7))*64 + b0w;
          ull a0,a1,a2,a3;
          for(;;){
            a0 = ALD8(yp+0); a1 = ALD8(yp+1); a2 = ALD8(yp+2); a3 = ALD8(yp+3);
            uint c0=(uint)(a0>>32), c1=(uint)(a1>>32), c2=(uint)(a2>>32), c3=(uint)(a3>>32);
            if (min(min(c0,c1),min(c2,c3)) >= 32u) break;
            __builtin_amdgcn_s_sleep(1);
          }
          dv[0] = fmaxf((float)(int)(uint)a0 * (1.f/YSCALE) - 32.f*YBIAS + bo2v, 0.f);
          dv[1] = fmaxf((float)(int)(uint)a1 * (1.f/YSCALE) - 32.f*YBIAS + bo2v, 0.f);
          dv[2] = fmaxf((float)(int)(uint)a2 * (1.f/YSCALE) - 32.f*YBIAS + bo2v, 0.f);
          dv[3] = fmaxf((float)(int)(uint)a3 * (1.f/YSCALE) - 32.f*YBIAS + bo2v, 0.f);
          if (wg == 0){
            #pragma unroll
            for (int i = 0; i < 4; ++i)
              out[(size_t)(b0w+i)*TT + (t-1)] = dv[i];
          }
        }
        #pragma unroll
        for (int i = 0; i < 4; ++i) pv4[i] = __shfl(dv[i], (l & 48));
      }
      f32x4 gR = *(const f32x4*)&S.gictx[0*1088 + col*68 + b0w];
      f32x4 gZ = *(const f32x4*)&S.gictx[1*1088 + col*68 + b0w];
      f32x4 gN = *(const f32x4*)&S.gictx[2*1088 + col*68 + b0w];
      float wc0 = S.wcol[0][col], wc1 = S.wcol[1][col], wc2 = S.wcol[2][col];
      float bhn = S.bhnN[col];
      #define E0(i, HC) { \
        float rr = sigm(gR[i] + pv4[i]*wc0 + acc0[i]); \
        float zz = sigm(gZ[i] + pv4[i]*wc1 + acc1[i]); \
        float nn = tanhf(gN[i] + pv4[i]*wc2 + rr*(acc2[i] + bhn)); \
        float h = (1.f-zz)*nn + zz*HC; \
        HC = h; \
        SWP(wP + (size_t)(b0w+(i))*512 + ng, pkh(h)); }
      E0(0,hc0) E0(1,hc1) E0(2,hc2) E0(3,hc3)
      #undef E0
      // zero-ahead of ring slot (t+4)&7 (ordered: drained below, then h0 flag)
      if (wg == 0 && tid < 64)
        SWP64(yring + ((size_t)((t+4) & 7))*64 + tid, 0ULL);
      drain_sync();
      if (tid < 64) FADDI(mbox + ((tid < 32) ? tid : tid + 32)*32 + 0);
    }
  } else if (role == 1){
    const uint* hp1 = hpk + 65536;
    for (int t = 0; t < TT; ++t){
      waitmail(myline + 0, 32*t, tid);       // h1[t-1] at LLC
      f32x4 acc0={0,0,0,0}, acc1={0,0,0,0}, acc2={0,0,0,0};
      DECL_LOADS(hp1)
      RUN16(MS3)
      float* gp = gh1raw + (size_t)j*3072 + v*256 + l*4;
      #pragma unroll
      for (int e = 0; e < 4; ++e){
        SWPF(gp + e,        acc0[e]);
        SWPF(gp + 1024 + e, acc1[e]);
        SWPF(gp + 2048 + e, acc2[e]);
      }
      drain_sync();
      if (tid < 32) FADDI(mbox + (64 + tid)*32 + 1);
    }
  } else if (role == 2){
    uint* p1 = hpk + 65536;
    float hc0 = 0.f, hc1 = 0.f, hc2 = 0.f, hc3 = 0.f;   // carried h1-old
    for (int t = 0; t < TT; ++t){
      const int w0 = (t & 1) ^ 1;
      waitmail(myline + 0, 32*(t+1), tid);   // h0[t] at LLC
      const uint* rP = hpk + w0*32768;
      f32x4 acc0={0,0,0,0}, acc1={0,0,0,0}, acc2={0,0,0,0};
      DECL_LOADS(rP)
      RUN16(MS3)
      waitmail(myline + 1, 32*(t+1), tid);   // gh1[t] at LLC (usually ready)
      const float* gp = gh1raw + (size_t)j*3072 + v*256 + l*4;
      f32x4 hR = { ALDF(gp+0),    ALDF(gp+1),    ALDF(gp+2),    ALDF(gp+3)    };
      f32x4 hZ = { ALDF(gp+1024), ALDF(gp+1025), ALDF(gp+1026), ALDF(gp+1027) };
      f32x4 hN = { ALDF(gp+2048), ALDF(gp+2049), ALDF(gp+2050), ALDF(gp+2051) };
      float bsR = S.bsumR[col], bsZ = S.bsumZ[col], biN = S.binN[col], bhN = S.bhnN[col];
      #define E1(i, HC) { \
        float r1 = sigm(acc0[i] + hR[i] + bsR); \
        float z1 = sigm(acc1[i] + hZ[i] + bsZ); \
        float n1 = tanhf(acc2[i] + biN + r1*(hN[i] + bhN)); \
        float h = (1.f-z1)*n1 + z1*HC; \
        HC = h; \
        SWP(p1 + (size_t)(b0w+(i))*512 + ng, pkh(h)); }
      E1(0,hc0) E1(1,hc1) E1(2,hc2) E1(3,hc3)
      #undef E1
      drain_sync();
      if (tid < 64) FADDI(mbox + ((tid < 32) ? (96 + tid) : tid)*32 + 0);
    }
  } else {
    const uint* hp1 = hpk + 65536;
    for (int t = 0; t < TT; ++t){
      waitmail(myline + 0, 32*(t+1), tid);   // h1[t] at LLC
      f32x4 acc0={0,0,0,0};
      DECL_LOADS(hp1)
      RUN16(MS1)
      float s0 = S.wo2v[col]*fmaxf(acc0[0] + S.bo1v[col], 0.f);
      float s1 = S.wo2v[col]*fmaxf(acc0[1] + S.bo1v[col], 0.f);
      float s2 = S.wo2v[col]*fmaxf(acc0[2] + S.bo1v[col], 0.f);
      float s3 = S.wo2v[col]*fmaxf(acc0[3] + S.bo1v[col], 0.f);
      #pragma unroll
      for (int d = 1; d < 16; d <<= 1){
        s0 += __shfl_xor(s0, d);
        s1 += __shfl_xor(s1, d);
        s2 += __shfl_xor(s2, d);
        s3 += __shfl_xor(s3, d);
      }
      if (col == 0){
        ull* yp = yring + ((size_t)(t & 7))*64 + b0w;
        FADD64(yp+0, (1ULL<<32) | (ull)(uint)(int)lrintf((s0 + YBIAS)*YSCALE));
        FADD64(yp+1, (1ULL<<32) | (ull)(uint)(int)lrintf((s1 + YBIAS)*YSCALE));
        FADD64(yp+2, (1ULL<<32) | (ull)(uint)(int)lrintf((s2 + YBIAS)*YSCALE));
        FADD64(yp+3, (1ULL<<32) | (ull)(uint)(int)lrintf((s3 + YBIAS)*YSCALE));
      }
      // no drain, no flag: the atomic IS the signal (count in high word)
    }
  }

  // ---------------- finale ----------------
  if (role == 0){
    waitmail(myline + 0, 32*TT, tid);
    if (wg == 0 && col == 0){
      // y[1023]: slot 1023&7 = 7
      const ull* yp = yring + 7*64 + b0w;
      ull a0,a1,a2,a3;
      for(;;){
        a0 = ALD8(yp+0); a1 = ALD8(yp+1); a2 = ALD8(yp+2); a3 = ALD8(yp+3);
        uint c0=(uint)(a0>>32), c1=(uint)(a1>>32), c2=(uint)(a2>>32), c3=(uint)(a3>>32);
        if (min(min(c0,c1),min(c2,c3)) >= 32u) break;
        __builtin_amdgcn_s_sleep(1);
      }
      out[(size_t)(b0w+0)*TT + 1023] = fmaxf((float)(int)(uint)a0*(1.f/YSCALE) - 32.f*YBIAS + bo2v, 0.f);
      out[(size_t)(b0w+1)*TT + 1023] = fmaxf((float)(int)(uint)a1*(1.f/YSCALE) - 32.f*YBIAS + bo2v, 0.f);
      out[(size_t)(b0w+2)*TT + 1023] = fmaxf((float)(int)(uint)a2*(1.f/YSCALE) - 32.f*YBIAS + bo2v, 0.f);
      out[(size_t)(b0w+3)*TT + 1023] = fmaxf((float)(int)(uint)a3*(1.f/YSCALE) - 32.f*YBIAS + bo2v, 0.f);
    }
    __syncthreads();
  } else if (role == 1){
    waitmail(mbox + (wg - 32)*32 + 0, 32*TT, tid);       // role0 line j: h0 done
  } else if (role == 2){
    waitmail(mbox + (96 + (wg - 64))*32 + 0, 32*TT, tid); // role3 line j: h1 done
  } else {
    waitmail(mbox + (wg - 96)*32 + 0, 32*TT, tid);       // role0 line j: h0 done
  }
  finfence(tid);   // one acquire: plain loads below must see LLC h-state
  #pragma unroll
  for (int k = 0; k < 2; ++k){
    int g = wg*512 + k*256 + tid;
    if (g < 32768) out[65536 + g] = unpk(hpk[g]);            // h0 final in buf0
    else           out[65536 + g] = unpk(hpk[65536 + (g - 32768)]);
  }
}

extern "C" void kernel_launch(void* const* d_in, const int* in_sizes, int n_in,
                              void* d_out, int out_size, void* d_ws, size_t ws_size,
                              hipStream_t stream){
  const float* ctx   = (const float*)d_in[0];
  const float* Wih0  = (const float*)d_in[2];
  const float* Whh0  = (const float*)d_in[3];
  const float* bih0  = (const float*)d_in[4];
  const float* bhh0  = (const float*)d_in[5];
  const float* Wih1  = (const float*)d_in[6];
  const float* Whh1  = (const float*)d_in[7];
  const float* bih1  = (const float*)d_in[8];
  const float* bhh1  = (const float*)d_in[9];
  const float* Wo1   = (const float*)d_in[10];
  const float* bo1   = (const float*)d_in[11];
  const float* Wo2   = (const float*)d_in[12];
  const float* bo2   = (const float*)d_in[13];

  (void)in_sizes; (void)n_in; (void)out_size; (void)ws_size;

  (void)hipFuncSetAttribute((const void*)decoder_rnn,
                            hipFuncAttributeMaxDynamicSharedMemorySize,
                            (int)sizeof(Smem));

  decoder_rnn<<<NWG, NT, sizeof(Smem), stream>>>(
      ctx, Wih0, Whh0, bih0, bhh0, Wih1, Whh1, bih1, bhh1,
      Wo1, bo1, Wo2, bo2, (float*)d_out, (float*)d_ws);
}

// Round 15
// 17184.883 us; speedup vs baseline: 1.5366x; 1.5366x over previous
//
#include <hip/hip_runtime.h>
#include <stdint.h>

// DecoderRNN R15: R12 base (proven 17.9ms) + two decomposed trims:
//  (1) register-carried h-old in roles 0/2 (lane rewrites same 4 (b,ng) elems
//      every step; validated by R14's passing run) - removes 4 scalar atomic
//      loads from each 512-dim hop.
//  (2) role2 waits gh1 flag BEFORE its MFMA chain (gh1 has a full step of
//      slack; flag is ~always set) and issues gh1 loads with the h0 loads -
//      removes post-MFMA wait + gh1 RTT from the binding hop.
// Everything else byte-identical to R12: mailbox p2p (per-consumer lines),
// swap stores -> LLC, sc0/sc1 coherent dwordx4 loads, no fences in loop,
// y partials via per-(parity,j,b) yout slots + flags.

#define NWG 128
#define NT  256
#define TT  1024

typedef unsigned short ushort;
typedef unsigned int   uint;
typedef unsigned long long ull;
typedef __attribute__((ext_vector_type(8))) short short8;
typedef __attribute__((ext_vector_type(4))) float f32x4;
typedef __attribute__((ext_vector_type(4))) uint  uint4v;

struct __align__(16) Smem {
  ushort wpl[2][48*520];
  float  gictx[3*16*68];
  float  wcol[3][16];
  float  bsumR[16], bsumZ[16], binN[16], bhnN[16];
  float  bo1v[16], wo2v[16];
  float  prevS[64];
};

__device__ __forceinline__ float sigm(float x){ return 1.f/(1.f + expf(-x)); }
__device__ __forceinline__ float bf2f(ushort h){ return __uint_as_float(((uint)h)<<16); }
__device__ __forceinline__ ushort bfrnd(float x){
  uint u = __float_as_uint(x);
  return (ushort)((u + 0x7fffu + ((u>>16)&1u)) >> 16);
}
__device__ __forceinline__ float unpk(uint p){
  return bf2f((ushort)(p >> 16)) + bf2f((ushort)(p & 0xffffu));
}
__device__ __forceinline__ uint pkh(float h){
  ushort hb = bfrnd(h);
  ushort lb = bfrnd(h - bf2f(hb));
  return ((uint)hb << 16) | (uint)lb;
}
__device__ __forceinline__ short8 hi8(uint4v a, uint4v b){
  uint d0 = __builtin_amdgcn_perm(a.y, a.x, 0x07060302u);
  uint d1 = __builtin_amdgcn_perm(a.w, a.z, 0x07060302u);
  uint d2 = __builtin_amdgcn_perm(b.y, b.x, 0x07060302u);
  uint d3 = __builtin_amdgcn_perm(b.w, b.z, 0x07060302u);
  return __builtin_bit_cast(short8, (uint4v){d0,d1,d2,d3});
}
__device__ __forceinline__ short8 lo8(uint4v a, uint4v b){
  uint d0 = __builtin_amdgcn_perm(a.y, a.x, 0x05040100u);
  uint d1 = __builtin_amdgcn_perm(a.w, a.z, 0x05040100u);
  uint d2 = __builtin_amdgcn_perm(b.y, b.x, 0x05040100u);
  uint d3 = __builtin_amdgcn_perm(b.w, b.z, 0x05040100u);
  return __builtin_bit_cast(short8, (uint4v){d0,d1,d2,d3});
}
#define SWP(p, v)  (void)__hip_atomic_exchange((uint*)(p), (uint)(v), __ATOMIC_RELAXED, __HIP_MEMORY_SCOPE_AGENT)
#define SWPF(p, v) SWP((p), __float_as_uint(v))
#define ALD1(p)    __hip_atomic_load((const uint*)(p), __ATOMIC_RELAXED, __HIP_MEMORY_SCOPE_AGENT)
#define ALDF(p)    __uint_as_float(ALD1(p))
#define FADDI(p)   (void)__hip_atomic_fetch_add((p), 1, __ATOMIC_RELAXED, __HIP_MEMORY_SCOPE_AGENT)

// init-only global barrier (poison-safe epochs)
__device__ __forceinline__ void gbar(int* slots, int* epoch, int w, int tid, int e){
  __syncthreads();
  if (tid == 0)
    __hip_atomic_store(&slots[w], e, __ATOMIC_RELEASE, __HIP_MEMORY_SCOPE_AGENT);
  if (w == 0 && tid < 64){
    for(;;){
      int m0 = __hip_atomic_load(&slots[tid*2+0], __ATOMIC_RELAXED, __HIP_MEMORY_SCOPE_AGENT);
      int m1 = __hip_atomic_load(&slots[tid*2+1], __ATOMIC_RELAXED, __HIP_MEMORY_SCOPE_AGENT);
      if (__all(min(m0,m1) >= e)) break;
      __builtin_amdgcn_s_sleep(1);
    }
    if (tid == 0){
      __builtin_amdgcn_fence(__ATOMIC_ACQUIRE, "agent");
      __hip_atomic_store(epoch, e, __ATOMIC_RELEASE, __HIP_MEMORY_SCOPE_AGENT);
    }
  }
  if (tid == 0){
    while (__hip_atomic_load(epoch, __ATOMIC_RELAXED, __HIP_MEMORY_SCOPE_AGENT) < e)
      __builtin_amdgcn_s_sleep(1);
    __builtin_amdgcn_fence(__ATOMIC_ACQUIRE, "agent");
  }
  __syncthreads();
}

__device__ __forceinline__ void drain_sync(){
  __builtin_amdgcn_s_waitcnt(0);
  __syncthreads();
}
// consumer poll: 1 lane, 1 dword, NO fence (loop loads are all LLC-coherent)
__device__ __forceinline__ void waitmail(const int* w, int target, int tid){
  if (tid == 0)
    while ((int)ALD1(w) < target) __builtin_amdgcn_s_sleep(1);
  __syncthreads();
}
__device__ __forceinline__ void finfence(int tid){
  if (tid == 0) __builtin_amdgcn_fence(__ATOMIC_ACQUIRE, "agent");
  __syncthreads();
}

// coherent LLC-direct 16B load (sc0 sc1 = bypass L1+L2)
#define LDSC(P, i) \
  asm volatile("global_load_dwordx4 %0, %1, off sc0 sc1" \
               : "=v"(pa##i) : "v"((P) + aoff + (i)*32)); \
  asm volatile("global_load_dwordx4 %0, %1, off sc0 sc1" \
               : "=v"(pb##i) : "v"((P) + aoff + (i)*32 + 4));
#define LD1SC(dst, addr) \
  asm volatile("global_load_dwordx4 %0, %1, off sc0 sc1" : "=v"(dst) : "v"(addr));
#define WB3(a,b,c) asm volatile("s_waitcnt vmcnt(0)" : "+v"(a),"+v"(b),"+v"(c));
#define VMBAR8(a,b,c,d,e,f,g,h) \
  asm volatile("s_waitcnt vmcnt(0)" \
               : "+v"(a),"+v"(b),"+v"(c),"+v"(d),"+v"(e),"+v"(f),"+v"(g),"+v"(h));
#define DECL_LOADS(P) \
  uint4v pa0,pa1,pa2,pa3,pa4,pa5,pa6,pa7,pa8,pa9,pa10,pa11,pa12,pa13,pa14,pa15; \
  uint4v pb0,pb1,pb2,pb3,pb4,pb5,pb6,pb7,pb8,pb9,pb10,pb11,pb12,pb13,pb14,pb15; \
  LDSC(P,0) LDSC(P,1) LDSC(P,2) LDSC(P,3) LDSC(P,4) LDSC(P,5) LDSC(P,6) LDSC(P,7) \
  LDSC(P,8) LDSC(P,9) LDSC(P,10) LDSC(P,11) LDSC(P,12) LDSC(P,13) LDSC(P,14) LDSC(P,15) \
  VMBAR8(pa0,pb0,pa1,pb1,pa2,pb2,pa3,pb3) \
  VMBAR8(pa4,pb4,pa5,pb5,pa6,pb6,pa7,pb7) \
  VMBAR8(pa8,pb8,pa9,pb9,pa10,pb10,pa11,pb11) \
  VMBAR8(pa12,pb12,pa13,pb13,pa14,pb14,pa15,pb15)

#define MS3(i) { \
  short8 AH_ = hi8(pa##i, pb##i); \
  short8 AL_ = lo8(pa##i, pb##i); \
  const int ko_ = (i)*32 + q*8; \
  short8 bh_ = *(const short8*)(&S.wpl[0][(col)*520 + ko_]); \
  short8 bl_ = *(const short8*)(&S.wpl[1][(col)*520 + ko_]); \
  acc0 = __builtin_amdgcn_mfma_f32_16x16x32_bf16(AH_, bh_, acc0, 0,0,0); \
  acc0 = __builtin_amdgcn_mfma_f32_16x16x32_bf16(AL_, bh_, acc0, 0,0,0); \
  acc0 = __builtin_amdgcn_mfma_f32_16x16x32_bf16(AH_, bl_, acc0, 0,0,0); \
  bh_ = *(const short8*)(&S.wpl[0][(16+col)*520 + ko_]); \
  bl_ = *(const short8*)(&S.wpl[1][(16+col)*520 + ko_]); \
  acc1 = __builtin_amdgcn_mfma_f32_16x16x32_bf16(AH_, bh_, acc1, 0,0,0); \
  acc1 = __builtin_amdgcn_mfma_f32_16x16x32_bf16(AL_, bh_, acc1, 0,0,0); \
  acc1 = __builtin_amdgcn_mfma_f32_16x16x32_bf16(AH_, bl_, acc1, 0,0,0); \
  bh_ = *(const short8*)(&S.wpl[0][(32+col)*520 + ko_]); \
  bl_ = *(const short8*)(&S.wpl[1][(32+col)*520 + ko_]); \
  acc2 = __builtin_amdgcn_mfma_f32_16x16x32_bf16(AH_, bh_, acc2, 0,0,0); \
  acc2 = __builtin_amdgcn_mfma_f32_16x16x32_bf16(AL_, bh_, acc2, 0,0,0); \
  acc2 = __builtin_amdgcn_mfma_f32_16x16x32_bf16(AH_, bl_, acc2, 0,0,0); }

#define MS1(i) { \
  short8 AH_ = hi8(pa##i, pb##i); \
  short8 AL_ = lo8(pa##i, pb##i); \
  const int ko_ = (i)*32 + q*8; \
  short8 bh_ = *(const short8*)(&S.wpl[0][(col)*520 + ko_]); \
  short8 bl_ = *(const short8*)(&S.wpl[1][(col)*520 + ko_]); \
  acc0 = __builtin_amdgcn_mfma_f32_16x16x32_bf16(AH_, bh_, acc0, 0,0,0); \
  acc0 = __builtin_amdgcn_mfma_f32_16x16x32_bf16(AL_, bh_, acc0, 0,0,0); \
  acc0 = __builtin_amdgcn_mfma_f32_16x16x32_bf16(AH_, bl_, acc0, 0,0,0); }

#define RUN16(M) M(0) M(1) M(2) M(3) M(4) M(5) M(6) M(7) \
                 M(8) M(9) M(10) M(11) M(12) M(13) M(14) M(15)

extern "C" __global__ void __launch_bounds__(NT, 1)
decoder_rnn(const float* __restrict__ ctx,   // [64][512]
            const float* __restrict__ Wih0,  // [1536][513] (row stride 513!)
            const float* __restrict__ Whh0,
            const float* __restrict__ bih0,
            const float* __restrict__ bhh0g,
            const float* __restrict__ Wih1,
            const float* __restrict__ Whh1,
            const float* __restrict__ bih1g,
            const float* __restrict__ bhh1g,
            const float* __restrict__ Wo1,
            const float* __restrict__ bo1g,
            const float* __restrict__ Wo2,
            const float* __restrict__ bo2g,
            float* __restrict__ out,         // [64*1024 y][65536 h_i]
            float* __restrict__ ws)
{
  extern __shared__ char smem_raw[];
  Smem& S = *reinterpret_cast<Smem*>(smem_raw);
  const int tid = threadIdx.x;
  const int wg  = blockIdx.x;

  uint*  hpk    = (uint*)ws;                 // h0pk 2x32768 | h1pk 32768
  float* gh1raw = (float*)ws + 98304;        // 32*3072
  float* yout   = (float*)ws + 196608;       // 2 x 2048
  int*   ibase  = (int*)((float*)ws + 200704);
  int*   gslots = ibase;                     // [128] init gbar
  int*   epoch  = ibase + 128;
  int*   mbox   = ibase + 256;               // 128 lines x 32 ints (128B/line)

  const float bo2v = bo2g[0];

  // ---------------- init (swaps -> LLC) ----------------
  for (int i = wg*NT + tid; i < 32768; i += NWG*NT){
    SWP(hpk + i, 0u);
    SWP(hpk + 65536 + i, 0u);
  }
  if (wg == 0)
    for (int i = tid; i < NWG*32; i += NT) SWP(mbox + i, 0);

  const int role = wg >> 5;
  const int j    = wg & 31;
  if (role != 3){
    const float* Wsrc = (role == 0) ? Whh0 : (role == 1) ? Whh1 : Wih1;
    for (int i = tid; i < 48*512; i += NT){
      int r = i >> 9, k = i & 511;
      int g = r >> 4, n = r & 15;
      float wv = Wsrc[(size_t)(g*512 + 16*j + n)*512 + k];
      ushort hh = bfrnd(wv);
      S.wpl[0][r*520 + k] = hh;
      S.wpl[1][r*520 + k] = bfrnd(wv - bf2f(hh));
    }
  } else {
    for (int i = tid; i < 16*512; i += NT){
      int r = i >> 9, k = i & 511;
      float wv = Wo1[(size_t)(16*j + r)*512 + k];
      ushort hh = bfrnd(wv);
      S.wpl[0][r*520 + k] = hh;
      S.wpl[1][r*520 + k] = bfrnd(wv - bf2f(hh));
    }
    if (tid < 16){ S.bo1v[tid] = bo1g[16*j + tid]; S.wo2v[tid] = Wo2[16*j + tid]; }
  }
  if (role == 0){
    if (tid < 48){
      int g = tid >> 4, n = tid & 15;
      S.wcol[g][n] = Wih0[(size_t)(g*512 + 16*j + n)*513 + 512];
    }
    if (tid < 16) S.bhnN[tid] = bhh0g[2*512 + 16*j + tid];
    for (int idx = tid; idx < 3072; idx += NT){
      int r = idx >> 6, b = idx & 63;
      int g = r >> 4, n = r & 15;
      int grow = g*512 + 16*j + n;
      const float* wr = Wih0 + (size_t)grow*513;
      const float* cx = ctx  + (size_t)b*512;
      float s = bih0[grow];
      if (g < 2) s += bhh0g[grow];
      #pragma unroll 4
      for (int k = 0; k < 512; ++k) s += wr[k]*cx[k];
      S.gictx[g*1088 + n*68 + b] = s;
    }
  }
  if (role == 2 && tid < 16){
    int n = tid;
    S.bsumR[n] = bih1g[16*j + n]       + bhh1g[16*j + n];
    S.bsumZ[n] = bih1g[512 + 16*j + n] + bhh1g[512 + 16*j + n];
    S.binN[n]  = bih1g[1024 + 16*j + n];
    S.bhnN[n]  = bhh1g[1024 + 16*j + n];
  }

  gbar(gslots, epoch, wg, tid, 1);

  int* myline = mbox + wg*32;

  const int v   = tid >> 6;
  const int l   = tid & 63;
  const int q   = l >> 4;
  const int col = l & 15;
  const int aoff = (16*v + col)*512 + q*8;
  const int b0w  = 16*v + 4*q;
  const int ng   = 16*j + col;

  if (role == 0){
    float hc0 = 0.f, hc1 = 0.f, hc2 = 0.f, hc3 = 0.f;   // carried h0-old
    for (int t = 0; t < TT; ++t){
      const int r0 = t & 1, w0 = r0 ^ 1;
      waitmail(myline + 0, 32*t, tid);       // h0[t-1] peers at LLC
      const uint* rP = hpk + r0*32768;
      uint*       wP = hpk + w0*32768;
      f32x4 acc0={0,0,0,0}, acc1={0,0,0,0}, acc2={0,0,0,0};
      DECL_LOADS(rP)
      RUN16(MS3)
      waitmail(myline + 1, 32*t, tid);       // y[t-1] partials at LLC
      if (tid < 64){
        float s = 0.f;
        if (t > 0){
          const float* yp = yout + ((t-1)&1)*2048 + tid;
          #pragma unroll
          for (int jj = 0; jj < 32; ++jj) s += ALDF(yp + jj*64);
        }
        float pv = fmaxf(s + bo2v, 0.f);
        S.prevS[tid] = pv;
        if (wg == 0 && t > 0) out[(size_t)tid*TT + (t-1)] = pv;
      }
      __syncthreads();
      f32x4 pv4 = *(const f32x4*)&S.prevS[b0w];
      f32x4 gR = *(const f32x4*)&S.gictx[0*1088 + col*68 + b0w];
      f32x4 gZ = *(const f32x4*)&S.gictx[1*1088 + col*68 + b0w];
      f32x4 gN = *(const f32x4*)&S.gictx[2*1088 + col*68 + b0w];
      float wc0 = S.wcol[0][col], wc1 = S.wcol[1][col], wc2 = S.wcol[2][col];
      float bhn = S.bhnN[col];
      #define E0(i, HC) { \
        float rr = sigm(gR[i] + pv4[i]*wc0 + acc0[i]); \
        float zz = sigm(gZ[i] + pv4[i]*wc1 + acc1[i]); \
        float nn = tanhf(gN[i] + pv4[i]*wc2 + rr*(acc2[i] + bhn)); \
        float h = (1.f-zz)*nn + zz*HC; \
        HC = h; \
        SWP(wP + (size_t)(b0w+(i))*512 + ng, pkh(h)); }
      E0(0,hc0) E0(1,hc1) E0(2,hc2) E0(3,hc3)
      #undef E0
      drain_sync();
      if (tid < 64) FADDI(mbox + ((tid < 32) ? tid : tid + 32)*32 + 0);
    }
  } else if (role == 1){
    const uint* hp1 = hpk + 65536;
    for (int t = 0; t < TT; ++t){
      waitmail(myline + 0, 32*t, tid);       // h1[t-1] at LLC
      f32x4 acc0={0,0,0,0}, acc1={0,0,0,0}, acc2={0,0,0,0};
      DECL_LOADS(hp1)
      RUN16(MS3)
      float* gp = gh1raw + (size_t)j*3072 + v*256 + l*4;
      #pragma unroll
      for (int e = 0; e < 4; ++e){
        SWPF(gp + e,        acc0[e]);
        SWPF(gp + 1024 + e, acc1[e]);
        SWPF(gp + 2048 + e, acc2[e]);
      }
      drain_sync();
      if (tid < 32) FADDI(mbox + (64 + tid)*32 + 1);
    }
  } else if (role == 2){
    uint* p1 = hpk + 65536;
    float hc0 = 0.f, hc1 = 0.f, hc2 = 0.f, hc3 = 0.f;   // carried h1-old
    for (int t = 0; t < TT; ++t){
      const int w0 = (t & 1) ^ 1;
      waitmail(myline + 0, 32*(t+1), tid);   // h0[t] at LLC
      waitmail(myline + 1, 32*(t+1), tid);   // gh1[t] (one step slack: ~free)
      const uint* rP = hpk + w0*32768;
      const float* gp = gh1raw + (size_t)j*3072 + v*256 + l*4;
      // issue gh1 loads first; they complete under DECL_LOADS' vmcnt(0)
      uint4v hRv, hZv, hNv;
      LD1SC(hRv, (const uint*)(gp + 0))
      LD1SC(hZv, (const uint*)(gp + 1024))
      LD1SC(hNv, (const uint*)(gp + 2048))
      f32x4 acc0={0,0,0,0}, acc1={0,0,0,0}, acc2={0,0,0,0};
      DECL_LOADS(rP)
      WB3(hRv, hZv, hNv)
      RUN16(MS3)
      f32x4 hR = __builtin_bit_cast(f32x4, hRv);
      f32x4 hZ = __builtin_bit_cast(f32x4, hZv);
      f32x4 hN = __builtin_bit_cast(f32x4, hNv);
      float bsR = S.bsumR[col], bsZ = S.bsumZ[col], biN = S.binN[col], bhN = S.bhnN[col];
      #define E1(i, HC) { \
        float r1 = sigm(acc0[i] + hR[i] + bsR); \
        float z1 = sigm(acc1[i] + hZ[i] + bsZ); \
        float n1 = tanhf(acc2[i] + biN + r1*(hN[i] + bhN)); \
        float h = (1.f-z1)*n1 + z1*HC; \
        HC = h; \
        SWP(p1 + (size_t)(b0w+(i))*512 + ng, pkh(h)); }
      E1(0,hc0) E1(1,hc1) E1(2,hc2) E1(3,hc3)
      #undef E1
      drain_sync();
      if (tid < 64) FADDI(mbox + ((tid < 32) ? (96 + tid) : tid)*32 + 0);
    }
  } else {
    const uint* hp1 = hpk + 65536;
    for (int t = 0; t < TT; ++t){
      waitmail(myline + 0, 32*(t+1), tid);   // h1[t] at LLC
      f32x4 acc0={0,0,0,0};
      DECL_LOADS(hp1)
      RUN16(MS1)
      float s0 = S.wo2v[col]*fmaxf(acc0[0] + S.bo1v[col], 0.f);
      float s1 = S.wo2v[col]*fmaxf(acc0[1] + S.bo1v[col], 0.f);
      float s2 = S.wo2v[col]*fmaxf(acc0[2] + S.bo1v[col], 0.f);
      float s3 = S.wo2v[col]*fmaxf(acc0[3] + S.bo1v[col], 0.f);
      #pragma unroll
      for (int d = 1; d < 16; d <<= 1){
        s0 += __shfl_xor(s0, d);
        s1 += __shfl_xor(s1, d);
        s2 += __shfl_xor(s2, d);
        s3 += __shfl_xor(s3, d);
      }
      if (col == 0){
        float* rp = yout + (t&1)*2048 + j*64 + b0w;
        SWPF(rp + 0, s0); SWPF(rp + 1, s1); SWPF(rp + 2, s2); SWPF(rp + 3, s3);
      }
      drain_sync();
      if (tid < 32) FADDI(mbox + tid*32 + 1);
    }
  }

  // ---------------- finale ----------------
  if (role == 0){
    waitmail(myline + 0, 32*TT, tid);
    if (wg == 0){
      waitmail(myline + 1, 32*TT, tid);
      if (tid < 64){
        float s = 0.f;
        const float* yp = yout + 2048 + tid;   // parity of t=1023 is 1
        #pragma unroll
        for (int jj = 0; jj < 32; ++jj) s += ALDF(yp + jj*64);
        out[(size_t)tid*TT + 1023] = fmaxf(s + bo2v, 0.f);
      }
    }
  } else if (role == 1){
    waitmail(mbox + (wg - 32)*32 + 0, 32*TT, tid);
  } else if (role == 2){
    waitmail(mbox + (96 + (wg - 64))*32 + 0, 32*TT, tid);
  }
  finfence(tid);   // one acquire: plain loads below must see LLC h-state
  #pragma unroll
  for (int k = 0; k < 2; ++k){
    int g = wg*512 + k*256 + tid;
    if (g < 32768) out[65536 + g] = unpk(hpk[g]);            // h0 final in buf0
    else           out[65536 + g] = unpk(hpk[65536 + (g - 32768)]);
  }
}

extern "C" void kernel_launch(void* const* d_in, const int* in_sizes, int n_in,
                              void* d_out, int out_size, void* d_ws, size_t ws_size,
                              hipStream_t stream){
  const float* ctx   = (const float*)d_in[0];
  const float* Wih0  = (const float*)d_in[2];
  const float* Whh0  = (const float*)d_in[3];
  const float* bih0  = (const float*)d_in[4];
  const float* bhh0  = (const float*)d_in[5];
  const float* Wih1  = (const float*)d_in[6];
  const float* Whh1  = (const float*)d_in[7];
  const float* bih1  = (const float*)d_in[8];
  const float* bhh1  = (const float*)d_in[9];
  const float* Wo1   = (const float*)d_in[10];
  const float* bo1   = (const float*)d_in[11];
  const float* Wo2   = (const float*)d_in[12];
  const float* bo2   = (const float*)d_in[13];

  (void)in_sizes; (void)n_in; (void)out_size; (void)ws_size;

  (void)hipFuncSetAttribute((const void*)decoder_rnn,
                            hipFuncAttributeMaxDynamicSharedMemorySize,
                            (int)sizeof(Smem));

  decoder_rnn<<<NWG, NT, sizeof(Smem), stream>>>(
      ctx, Wih0, Whh0, bih0, bhh0, Wih1, Whh1, bih1, bhh1,
      Wo1, bo1, Wo2, bo2, (float*)d_out, (float*)d_ws);
}